// Round 6
// baseline (278.893 us; speedup 1.0000x reference)
//
#include <hip/hip_runtime.h>
#include <hip/hip_bf16.h>

#define N_NODES 100000
#define N_EDGES 1600000
#define NBUCK 391          // ceil(N_NODES / 256): bucket = 256-node dst range
#define BCAP 5120          // per-bucket capacity (expected 4096, sigma ~64)
#define ACHUNK 4096        // edges per partA block

typedef __bf16 bf16x8 __attribute__((ext_vector_type(8)));
typedef __bf16 bf16x4 __attribute__((ext_vector_type(4)));
typedef float  f32x4  __attribute__((ext_vector_type(4)));
typedef float  f32x2  __attribute__((ext_vector_type(2)));

// Feature permutation for P/R/H rows: feature f lives at position
// pos(f) = (f&15)*8 + (f>>4). Layer-2 weight swizzle + head weights absorb it.
// P has N+1 rows: row N is an all-zero sentinel row for padded edge slots.

// ---------------- preprocessing: 2-level radix partition of edges by dst ----------------

__global__ __launch_bounds__(512) void zerob_kernel(int* __restrict__ bcnt,
                                                    int* __restrict__ Psent) {
  int t = threadIdx.x;
  if (t < NBUCK) bcnt[t] = 0;
  if (t >= 480) Psent[t - 480] = 0;   // 32 dwords = 128 B = fp8 row N of P
}

__global__ __launch_bounds__(256) void partA_kernel(const int* __restrict__ src,
                                                    const int* __restrict__ dst,
                                                    int* __restrict__ bcnt,
                                                    unsigned* __restrict__ packed, int E) {
  __shared__ int hist[NBUCK];
  __shared__ int curs[NBUCK];
  const int t = threadIdx.x;
  for (int i = t; i < NBUCK; i += 256) hist[i] = 0;
  __syncthreads();

  const int base = blockIdx.x * ACHUNK;
  const int lim = min(base + ACHUNK, E);

  int dloc[16], sloc[16];
  int myn = 0;
  for (int i = base + t; i < lim; i += 256) {
    dloc[myn] = dst[i];
    sloc[myn] = src[i];
    ++myn;
  }
  for (int k = 0; k < myn; ++k) atomicAdd(&hist[dloc[k] >> 8], 1);
  __syncthreads();

  for (int i = t; i < NBUCK; i += 256) {
    int h = hist[i];
    curs[i] = (h > 0) ? atomicAdd(&bcnt[i], h) : 0;
  }
  __syncthreads();

  for (int k = 0; k < myn; ++k) {
    int d = dloc[k];
    int b = d >> 8;
    int pos = atomicAdd(&curs[b], 1);
    if (pos < BCAP)
      packed[(size_t)b * BCAP + pos] = ((unsigned)sloc[k] << 8) | (unsigned)(d & 255);
  }
}

__global__ __launch_bounds__(256) void partBh_kernel(const unsigned* __restrict__ packed,
                                                     const int* __restrict__ bcnt,
                                                     int* __restrict__ pcnt,
                                                     int* __restrict__ deg,
                                                     int* __restrict__ pbt, int N) {
  __shared__ int hist[256];
  __shared__ int red[256];
  const int b = blockIdx.x, t = threadIdx.x;
  hist[t] = 0;
  __syncthreads();
  const int ecnt = min(bcnt[b], BCAP);
  const unsigned* pk = packed + (size_t)b * BCAP;
  for (int i = t; i < ecnt; i += 256) atomicAdd(&hist[pk[i] & 255u], 1);
  __syncthreads();
  int c = hist[t];
  int node = b * 256 + t;
  int pc = (node < N) ? ((c + 3) & ~3) : 0;
  if (node < N) { deg[node] = c; pcnt[node] = pc; }
  red[t] = pc;
  __syncthreads();
  for (int d = 128; d > 0; d >>= 1) {
    if (t < d) red[t] += red[t + d];
    __syncthreads();
  }
  if (t == 0) pbt[b] = red[0];
}

__global__ __launch_bounds__(512) void bscan_kernel(const int* __restrict__ pbt,
                                                    int* __restrict__ bbase,
                                                    int* __restrict__ offs, int N) {
  __shared__ int tmp[512];
  int t = threadIdx.x;
  int v = (t < NBUCK) ? pbt[t] : 0;
  int x = v;
  tmp[t] = x;
  __syncthreads();
  for (int d = 1; d < 512; d <<= 1) {
    int y = (t >= d) ? tmp[t - d] : 0;
    __syncthreads();
    x += y;
    tmp[t] = x;
    __syncthreads();
  }
  if (t < NBUCK) bbase[t] = x - v;
  if (t == NBUCK - 1) offs[N] = x;
}

__global__ __launch_bounds__(256) void partBs_kernel(const unsigned* __restrict__ packed,
                                                     const int* __restrict__ bcnt,
                                                     const int* __restrict__ bbase,
                                                     const int* __restrict__ pcnt,
                                                     const int* __restrict__ deg,
                                                     int* __restrict__ offs,
                                                     int* __restrict__ ssrc, int N) {
  __shared__ int scanbuf[256];
  __shared__ int curs[256];
  const int b = blockIdx.x, t = threadIdx.x;
  const int node = b * 256 + t;
  int pc = (node < N) ? pcnt[node] : 0;
  int c  = (node < N) ? deg[node] : 0;
  int x = pc;
  scanbuf[t] = x;
  __syncthreads();
  for (int d = 1; d < 256; d <<= 1) {
    int y = (t >= d) ? scanbuf[t - d] : 0;
    __syncthreads();
    x += y;
    scanbuf[t] = x;
    __syncthreads();
  }
  int excl = x - pc;
  const int obase = bbase[b];
  if (node < N) offs[node] = obase + excl;
  curs[t] = excl;
  __syncthreads();

  const int ecnt = min(bcnt[b], BCAP);
  const unsigned* pk = packed + (size_t)b * BCAP;
  for (int i = t; i < ecnt; i += 256) {
    unsigned p = pk[i];
    int r = atomicAdd(&curs[p & 255u], 1);
    ssrc[obase + r] = (int)(p >> 8);
  }
  for (int j = c; j < pc; ++j) ssrc[obase + excl + j] = N;
}

// -------- weight swizzle: W[128][256] (=[Wl|Wr]) -> MFMA B-fragment order --------

__global__ __launch_bounds__(256) void wswz_kernel(const float* __restrict__ Wl1,
                                                   const float* __restrict__ Wr1,
                                                   const float* __restrict__ Wl2,
                                                   const float* __restrict__ Wr2,
                                                   __bf16* __restrict__ W1out,
                                                   __bf16* __restrict__ W2out) {
  int gi = blockIdx.x * blockDim.x + threadIdx.x;  // 0..65535
  bool L2 = gi >= 32768;
  int i = gi & 32767;
  int j = i & 7;
  int lane = (i >> 3) & 63;
  int c = (i >> 9) & 3;
  int tile = i >> 11;
  int k = c * 32 + ((lane >> 4) * 8) + j;
  int krow = L2 ? (((k & 7) << 4) | (k >> 3)) : k;
  int col = tile * 16 + (lane & 15);
  const float* Wl = L2 ? Wl2 : Wl1;
  const float* Wr = L2 ? Wr2 : Wr1;
  float v = (col < 128) ? Wl[krow * 128 + col] : Wr[krow * 128 + (col - 128)];
  (L2 ? W2out : W1out)[i] = (__bf16)v;
}

// ---------------- fused GEMM: [P | R] = A @ [Wl | Wr] (+bias on R) ----------------
// Persistent, LDS-free, barrier-free. Wave w (0..3) owns col-tiles 4w..4w+3 (64 cols)
// and keeps its 16 B-fragments in registers across all row tiles. Per 64-row tile:
// 16 independent a-frag loads + 64 MFMA + 16 small stores. NOTE: R must NOT alias A.

template <bool A_IS_F32>
__global__ __launch_bounds__(256, 2) void gemm_kernel(const void* __restrict__ Aptr,
                                                      const __bf16* __restrict__ Wswz,
                                                      const float* __restrict__ bias,
                                                      unsigned char* __restrict__ P,
                                                      __bf16* __restrict__ R, int M,
                                                      int tiles, int stride) {
  const int t = threadIdx.x;
  const int lane = t & 63;
  const int w = t >> 6;        // col-group: tiles 4w..4w+3
  const int q = lane >> 4;
  const int s = lane & 15;

  // B fragments: resident for the whole kernel (64 VGPRs)
  bf16x8 bfrag[16];
#pragma unroll
  for (int ct = 0; ct < 4; ++ct)
#pragma unroll
    for (int c = 0; c < 4; ++c)
      bfrag[ct * 4 + c] =
          *(const bf16x8*)&Wswz[(size_t)((((w * 4 + ct) * 4 + c) * 64) + lane) * 8];

  float breg[4];
#pragma unroll
  for (int j = 0; j < 4; ++j)
    breg[j] = (w >= 2) ? bias[((w - 2) * 4 + j) * 16 + s] : 0.f;

  for (int tile = blockIdx.x; tile < tiles; tile += stride) {
    const int m0 = tile * 64;

    bf16x8 afrag[16];
    if (A_IS_F32) {
      const float* A = (const float*)Aptr;
#pragma unroll
      for (int rt = 0; rt < 4; ++rt) {
        int rc = min(m0 + rt * 16 + s, M - 1);
#pragma unroll
        for (int c = 0; c < 4; ++c) {
          const float* p = &A[(size_t)rc * 128 + c * 32 + q * 8];
          float4 v0 = *(const float4*)p;
          float4 v1 = *(const float4*)(p + 4);
          bf16x8 a;
          a[0] = (__bf16)v0.x; a[1] = (__bf16)v0.y; a[2] = (__bf16)v0.z; a[3] = (__bf16)v0.w;
          a[4] = (__bf16)v1.x; a[5] = (__bf16)v1.y; a[6] = (__bf16)v1.z; a[7] = (__bf16)v1.w;
          afrag[rt * 4 + c] = a;
        }
      }
    } else {
      const __bf16* A = (const __bf16*)Aptr;
#pragma unroll
      for (int rt = 0; rt < 4; ++rt) {
        int rc = min(m0 + rt * 16 + s, M - 1);
#pragma unroll
        for (int c = 0; c < 4; ++c)
          afrag[rt * 4 + c] = *(const bf16x8*)&A[(size_t)rc * 128 + c * 32 + q * 8];
      }
    }

    f32x4 acc[16];
    f32x4 zero = {0.f, 0.f, 0.f, 0.f};
#pragma unroll
    for (int i = 0; i < 16; ++i) acc[i] = zero;

#pragma unroll
    for (int c = 0; c < 4; ++c)
#pragma unroll
      for (int rt = 0; rt < 4; ++rt)
#pragma unroll
        for (int ct = 0; ct < 4; ++ct)
          acc[rt * 4 + ct] = __builtin_amdgcn_mfma_f32_16x16x32_bf16(
              afrag[rt * 4 + c], bfrag[ct * 4 + c], acc[rt * 4 + ct], 0, 0, 0);

    // C/D: row = m0 + rt*16 + q*4 + r, col = (4w+ct)*16 + s -> pos s*8 + 4w+ct
#pragma unroll
    for (int rt = 0; rt < 4; ++rt) {
#pragma unroll
      for (int r = 0; r < 4; ++r) {
        int row = m0 + rt * 16 + q * 4 + r;
        if (row < M) {
          if (w < 2) {
            unsigned v = 0;
            v = __builtin_amdgcn_cvt_pk_fp8_f32(acc[rt * 4 + 0][r], acc[rt * 4 + 1][r], v, false);
            v = __builtin_amdgcn_cvt_pk_fp8_f32(acc[rt * 4 + 2][r], acc[rt * 4 + 3][r], v, true);
            *(unsigned*)&P[(size_t)row * 128 + s * 8 + w * 4] = v;
          } else {
            bf16x4 o;
#pragma unroll
            for (int ct = 0; ct < 4; ++ct) o[ct] = (__bf16)(acc[rt * 4 + ct][r] + breg[ct]);
            *(bf16x4*)&R[(size_t)row * 128 + s * 8 + (w - 2) * 4] = o;
          }
        }
      }
    }
  }
}

// ------------- aggregation: H = relu(mean_agg(P) + R); FINAL fuses heads -------------
// 4 nodes per wave (one per 16-lane group). Padded+sentinel edge lists: branch-free
// gather, aligned dwordx4 ssrc loads, no cross-group reduce, all-lane stores.

template <bool FINAL>
__global__ __launch_bounds__(256) void agg_kernel(
    const unsigned char* __restrict__ P, const __bf16* R,
    const int* __restrict__ offs, const int* __restrict__ deg,
    const int* __restrict__ ssrc,
    __bf16* H, float* __restrict__ out,
    const float* __restrict__ Wp, const float* __restrict__ Wd,
    const float* __restrict__ bp, const float* __restrict__ bd, int n) {
  int w4 = (int)((blockIdx.x * blockDim.x + threadIdx.x) >> 6);
  int lane = threadIdx.x & 63;
  int g = lane >> 4;
  int s = lane & 15;
  int node = w4 * 4 + g;
  int nc = min(node, n - 1);
  int start = offs[nc];
  int pend = offs[nc + 1];

  f32x2 a01 = {0.f, 0.f}, a23 = {0.f, 0.f}, a45 = {0.f, 0.f}, a67 = {0.f, 0.f};

  const unsigned char* Pb = P + (size_t)s * 8;
  for (int cur = start; cur < pend; cur += 4) {
    uint4 sv = *(const uint4*)&ssrc[cur];
    uint2 v0 = *(const uint2*)(Pb + (size_t)sv.x * 128);
    uint2 v1 = *(const uint2*)(Pb + (size_t)sv.y * 128);
    uint2 v2 = *(const uint2*)(Pb + (size_t)sv.z * 128);
    uint2 v3 = *(const uint2*)(Pb + (size_t)sv.w * 128);
    a01 += __builtin_amdgcn_cvt_pk_f32_fp8(v0.x, false);
    a23 += __builtin_amdgcn_cvt_pk_f32_fp8(v0.x, true);
    a45 += __builtin_amdgcn_cvt_pk_f32_fp8(v0.y, false);
    a67 += __builtin_amdgcn_cvt_pk_f32_fp8(v0.y, true);
    a01 += __builtin_amdgcn_cvt_pk_f32_fp8(v1.x, false);
    a23 += __builtin_amdgcn_cvt_pk_f32_fp8(v1.x, true);
    a45 += __builtin_amdgcn_cvt_pk_f32_fp8(v1.y, false);
    a67 += __builtin_amdgcn_cvt_pk_f32_fp8(v1.y, true);
    a01 += __builtin_amdgcn_cvt_pk_f32_fp8(v2.x, false);
    a23 += __builtin_amdgcn_cvt_pk_f32_fp8(v2.x, true);
    a45 += __builtin_amdgcn_cvt_pk_f32_fp8(v2.y, false);
    a67 += __builtin_amdgcn_cvt_pk_f32_fp8(v2.y, true);
    a01 += __builtin_amdgcn_cvt_pk_f32_fp8(v3.x, false);
    a23 += __builtin_amdgcn_cvt_pk_f32_fp8(v3.x, true);
    a45 += __builtin_amdgcn_cvt_pk_f32_fp8(v3.y, false);
    a67 += __builtin_amdgcn_cvt_pk_f32_fp8(v3.y, true);
  }

  int dg = deg[nc];
  float inv = 1.0f / (float)(dg > 0 ? dg : 1);

  bf16x8 rv = *(const bf16x8*)&R[(size_t)nc * 128 + s * 8];
  float acc[8] = {a01[0], a01[1], a23[0], a23[1], a45[0], a45[1], a67[0], a67[1]};
  float h[8];
#pragma unroll
  for (int j = 0; j < 8; ++j) {
    h[j] = fmaxf(acc[j] * inv + (float)rv[j], 0.f);
  }

  if (!FINAL) {
    if (node < n) {
      bf16x8 o;
#pragma unroll
      for (int j = 0; j < 8; ++j) o[j] = (__bf16)h[j];
      *(bf16x8*)&H[(size_t)node * 128 + s * 8] = o;
    }
  } else {
    float p = 0.f, dd = 0.f;
#pragma unroll
    for (int j = 0; j < 8; ++j) {
      p += h[j] * Wp[j * 16 + s];
      dd += h[j] * Wd[j * 16 + s];
    }
    p += __shfl_xor(p, 1, 64);  p += __shfl_xor(p, 2, 64);
    p += __shfl_xor(p, 4, 64);  p += __shfl_xor(p, 8, 64);
    dd += __shfl_xor(dd, 1, 64); dd += __shfl_xor(dd, 2, 64);
    dd += __shfl_xor(dd, 4, 64); dd += __shfl_xor(dd, 8, 64);
    if (node < n && s == 0) {
      float preds = p + bp[0];
      float sg = 1.0f / (1.0f + __expf(-(dd + bd[0])));
      out[node] = preds - sg;
      out[n + node] = preds + sg;
    }
  }
}

// ----------------------------------- launch -----------------------------------

extern "C" void kernel_launch(void* const* d_in, const int* in_sizes, int n_in,
                              void* d_out, int out_size, void* d_ws, size_t ws_size,
                              hipStream_t stream) {
  const float* x    = (const float*)d_in[0];
  const int*   ei   = (const int*)d_in[1];
  const float* Wl1 = (const float*)d_in[2];
  const float* Wr1 = (const float*)d_in[3];
  const float* b1  = (const float*)d_in[4];
  const float* Wl2 = (const float*)d_in[5];
  const float* Wr2 = (const float*)d_in[6];
  const float* b2  = (const float*)d_in[7];
  const float* Wp  = (const float*)d_in[8];
  const float* bp  = (const float*)d_in[9];
  const float* Wd  = (const float*)d_in[10];
  const float* bd  = (const float*)d_in[11];
  float* out = (float*)d_out;

  const int N = N_NODES, E = N_EDGES;
  const int* src = ei;
  const int* dst = ei + E;
  const size_t PADE = (size_t)E + 3 * (size_t)N + 64;

  char* w = (char*)d_ws;
  unsigned char* P = (unsigned char*)w; w += (size_t)(N + 1) * 128;  // fp8, +sentinel row
  __bf16* R1     = (__bf16*)w;   w += (size_t)N * 128 * 2;           // R1 -> H1 (in place)
  __bf16* R2     = (__bf16*)w;   w += (size_t)N * 128 * 2;           // R2 (no aliasing w/ H1)
  int* ssrc      = (int*)w;      w += PADE * 4;
  unsigned* pck  = (unsigned*)w; w += (size_t)NBUCK * BCAP * 4;      // 8.0 MB
  int* bcnt      = (int*)w;      w += 512 * 4;
  int* bbase     = (int*)w;      w += 512 * 4;
  int* pbt       = (int*)w;      w += 512 * 4;
  int* pcnt      = (int*)w;      w += (size_t)(N + 32) * 4;
  int* deg       = (int*)w;      w += (size_t)(N + 32) * 4;
  int* offs      = (int*)w;      w += (size_t)(N + 32) * 4;
  __bf16* Ws1    = (__bf16*)w;   w += 65536;
  __bf16* Ws2    = (__bf16*)w;   w += 65536;

  // graph preprocessing (shared by both layers)
  zerob_kernel<<<1, 512, 0, stream>>>(bcnt, (int*)(P + (size_t)N * 128));
  wswz_kernel<<<256, 256, 0, stream>>>(Wl1, Wr1, Wl2, Wr2, Ws1, Ws2);
  partA_kernel<<<(E + ACHUNK - 1) / ACHUNK, 256, 0, stream>>>(src, dst, bcnt, pck, E);
  partBh_kernel<<<NBUCK, 256, 0, stream>>>(pck, bcnt, pcnt, deg, pbt, N);
  bscan_kernel<<<1, 512, 0, stream>>>(pbt, bbase, offs, N);
  partBs_kernel<<<NBUCK, 256, 0, stream>>>(pck, bcnt, bbase, pcnt, deg, offs, ssrc, N);

  const int TILES = (N + 63) / 64;  // 1563
  const int GG = 512;               // persistent-ish grid: ~3 tiles/block
  const int AB = (N + 15) / 16;     // 6250 blocks, 4 nodes/wave
  // layer 1
  gemm_kernel<true><<<GG, 256, 0, stream>>>(x, Ws1, b1, P, R1, N, TILES, GG);
  agg_kernel<false><<<AB, 256, 0, stream>>>(P, R1, offs, deg, ssrc, R1, nullptr,
                                            nullptr, nullptr, nullptr, nullptr, N);
  // layer 2 + fused heads (R2 separate: persistent gemm has no staging barrier)
  gemm_kernel<false><<<GG, 256, 0, stream>>>(R1, Ws2, b2, P, R2, N, TILES, GG);
  agg_kernel<true><<<AB, 256, 0, stream>>>(P, R2, offs, deg, ssrc, nullptr, out,
                                           Wp, Wd, bp, bd, N);
}

// Round 7
// 278.632 us; speedup vs baseline: 1.0009x; 1.0009x over previous
//
#include <hip/hip_runtime.h>
#include <hip/hip_bf16.h>

#define N_NODES 100000
#define N_EDGES 1600000
#define NBUCK 391          // ceil(N_NODES / 256): bucket = 256-node dst range
#define BCAP 5120          // per-bucket capacity (expected 4096, sigma ~64)
#define ACHUNK 4096        // edges per partA block

typedef __bf16 bf16x8 __attribute__((ext_vector_type(8)));
typedef __bf16 bf16x4 __attribute__((ext_vector_type(4)));
typedef float  f32x4  __attribute__((ext_vector_type(4)));
typedef float  f32x2  __attribute__((ext_vector_type(2)));

// Feature permutation for P/R/H rows: feature f lives at position
// pos(f) = (f&15)*8 + (f>>4). Layer-2 weight swizzle + head weights absorb it.
// P1/P2 have N+1 rows: row N is an all-zero sentinel for padded edge slots.

// ---------------- preprocessing: 2-level radix partition of edges by dst ----------------

__global__ __launch_bounds__(512) void zerob_kernel(int* __restrict__ bcnt,
                                                    int* __restrict__ P1s,
                                                    int* __restrict__ P2s) {
  int t = threadIdx.x;
  if (t < NBUCK) bcnt[t] = 0;
  if (t >= 480) { P1s[t - 480] = 0; P2s[t - 480] = 0; }  // 32 dwords = 128 B each
}

__global__ __launch_bounds__(256) void partA_kernel(const int* __restrict__ src,
                                                    const int* __restrict__ dst,
                                                    int* __restrict__ bcnt,
                                                    unsigned* __restrict__ packed, int E) {
  __shared__ int hist[NBUCK];
  __shared__ int curs[NBUCK];
  const int t = threadIdx.x;
  for (int i = t; i < NBUCK; i += 256) hist[i] = 0;
  __syncthreads();

  const int base = blockIdx.x * ACHUNK;
  const int lim = min(base + ACHUNK, E);

  int dloc[16], sloc[16];
  int myn = 0;
  for (int i = base + t; i < lim; i += 256) {
    dloc[myn] = dst[i];
    sloc[myn] = src[i];
    ++myn;
  }
  for (int k = 0; k < myn; ++k) atomicAdd(&hist[dloc[k] >> 8], 1);
  __syncthreads();

  for (int i = t; i < NBUCK; i += 256) {
    int h = hist[i];
    curs[i] = (h > 0) ? atomicAdd(&bcnt[i], h) : 0;
  }
  __syncthreads();

  for (int k = 0; k < myn; ++k) {
    int d = dloc[k];
    int b = d >> 8;
    int pos = atomicAdd(&curs[b], 1);
    if (pos < BCAP)
      packed[(size_t)b * BCAP + pos] = ((unsigned)sloc[k] << 8) | (unsigned)(d & 255);
  }
}

__global__ __launch_bounds__(256) void partBh_kernel(const unsigned* __restrict__ packed,
                                                     const int* __restrict__ bcnt,
                                                     int* __restrict__ pcnt,
                                                     int* __restrict__ deg,
                                                     int* __restrict__ pbt, int N) {
  __shared__ int hist[256];
  __shared__ int red[256];
  const int b = blockIdx.x, t = threadIdx.x;
  hist[t] = 0;
  __syncthreads();
  const int ecnt = min(bcnt[b], BCAP);
  const unsigned* pk = packed + (size_t)b * BCAP;
  for (int i = t; i < ecnt; i += 256) atomicAdd(&hist[pk[i] & 255u], 1);
  __syncthreads();
  int c = hist[t];
  int node = b * 256 + t;
  int pc = (node < N) ? ((c + 3) & ~3) : 0;
  if (node < N) { deg[node] = c; pcnt[node] = pc; }
  red[t] = pc;
  __syncthreads();
  for (int d = 128; d > 0; d >>= 1) {
    if (t < d) red[t] += red[t + d];
    __syncthreads();
  }
  if (t == 0) pbt[b] = red[0];
}

__global__ __launch_bounds__(512) void bscan_kernel(const int* __restrict__ pbt,
                                                    int* __restrict__ bbase,
                                                    int* __restrict__ offs, int N) {
  __shared__ int tmp[512];
  int t = threadIdx.x;
  int v = (t < NBUCK) ? pbt[t] : 0;
  int x = v;
  tmp[t] = x;
  __syncthreads();
  for (int d = 1; d < 512; d <<= 1) {
    int y = (t >= d) ? tmp[t - d] : 0;
    __syncthreads();
    x += y;
    tmp[t] = x;
    __syncthreads();
  }
  if (t < NBUCK) bbase[t] = x - v;
  if (t == NBUCK - 1) offs[N] = x;
}

__global__ __launch_bounds__(256) void partBs_kernel(const unsigned* __restrict__ packed,
                                                     const int* __restrict__ bcnt,
                                                     const int* __restrict__ bbase,
                                                     const int* __restrict__ pcnt,
                                                     const int* __restrict__ deg,
                                                     int* __restrict__ offs,
                                                     int* __restrict__ ssrc, int N) {
  __shared__ int scanbuf[256];
  __shared__ int curs[256];
  const int b = blockIdx.x, t = threadIdx.x;
  const int node = b * 256 + t;
  int pc = (node < N) ? pcnt[node] : 0;
  int c  = (node < N) ? deg[node] : 0;
  int x = pc;
  scanbuf[t] = x;
  __syncthreads();
  for (int d = 1; d < 256; d <<= 1) {
    int y = (t >= d) ? scanbuf[t - d] : 0;
    __syncthreads();
    x += y;
    scanbuf[t] = x;
    __syncthreads();
  }
  int excl = x - pc;
  const int obase = bbase[b];
  if (node < N) offs[node] = obase + excl;
  curs[t] = excl;
  __syncthreads();

  const int ecnt = min(bcnt[b], BCAP);
  const unsigned* pk = packed + (size_t)b * BCAP;
  for (int i = t; i < ecnt; i += 256) {
    unsigned p = pk[i];
    int r = atomicAdd(&curs[p & 255u], 1);
    ssrc[obase + r] = (int)(p >> 8);
  }
  for (int j = c; j < pc; ++j) ssrc[obase + excl + j] = N;
}

// -------- weight swizzle: W[128][256] (=[Wl|Wr]) -> MFMA B-fragment order --------

__global__ __launch_bounds__(256) void wswz_kernel(const float* __restrict__ Wl1,
                                                   const float* __restrict__ Wr1,
                                                   const float* __restrict__ Wl2,
                                                   const float* __restrict__ Wr2,
                                                   __bf16* __restrict__ W1out,
                                                   __bf16* __restrict__ W2out) {
  int gi = blockIdx.x * blockDim.x + threadIdx.x;  // 0..65535
  bool L2 = gi >= 32768;
  int i = gi & 32767;
  int j = i & 7;
  int lane = (i >> 3) & 63;
  int c = (i >> 9) & 3;
  int tile = i >> 11;
  int k = c * 32 + ((lane >> 4) * 8) + j;
  int krow = L2 ? (((k & 7) << 4) | (k >> 3)) : k;
  int col = tile * 16 + (lane & 15);
  const float* Wl = L2 ? Wl2 : Wl1;
  const float* Wr = L2 ? Wr2 : Wr1;
  float v = (col < 128) ? Wl[krow * 128 + col] : Wr[krow * 128 + (col - 128)];
  (L2 ? W2out : W1out)[i] = (__bf16)v;
}

// ---------------- gemm1: [P1 | R1] = x @ [Wl1 | Wr1] (+bias on R1) ----------------
// Persistent 512 blocks. B-fragments register-resident (loaded once). A staged
// fp32->bf16 through LDS with fully-coalesced global reads (each tile read once).
// Wave w owns col-tiles 4w..4w+3 (64 cols).

__global__ __launch_bounds__(256, 2) void gemm1_kernel(const float* __restrict__ A,
                                                       const __bf16* __restrict__ Wswz,
                                                       const float* __restrict__ bias,
                                                       unsigned char* __restrict__ P,
                                                       __bf16* __restrict__ R, int M,
                                                       int tiles, int stride) {
  __shared__ __bf16 ldsA[64][136];
  const int t = threadIdx.x;
  const int lane = t & 63;
  const int w = t >> 6;
  const int q = lane >> 4;
  const int s = lane & 15;

  bf16x8 bfrag[16];
#pragma unroll
  for (int ct = 0; ct < 4; ++ct)
#pragma unroll
    for (int c = 0; c < 4; ++c)
      bfrag[ct * 4 + c] =
          *(const bf16x8*)&Wswz[(size_t)((((w * 4 + ct) * 4 + c) * 64) + lane) * 8];

  float breg[4];
#pragma unroll
  for (int j = 0; j < 4; ++j)
    breg[j] = (w >= 2) ? bias[((w - 2) * 4 + j) * 16 + s] : 0.f;

  for (int tile = blockIdx.x; tile < tiles; tile += stride) {
    const int m0 = tile * 64;

#pragma unroll
    for (int it = 0; it < 8; ++it) {
      int row = it * 8 + (t >> 5);
      int col = (t & 31) * 4;
      float4 v = make_float4(0.f, 0.f, 0.f, 0.f);
      if (m0 + row < M) v = *(const float4*)&A[(size_t)(m0 + row) * 128 + col];
      bf16x4 bv;
      bv.x = (__bf16)v.x; bv.y = (__bf16)v.y; bv.z = (__bf16)v.z; bv.w = (__bf16)v.w;
      *(bf16x4*)&ldsA[row][col] = bv;
    }
    __syncthreads();

    bf16x8 afrag[16];
#pragma unroll
    for (int rt = 0; rt < 4; ++rt)
#pragma unroll
      for (int c = 0; c < 4; ++c)
        afrag[rt * 4 + c] = *(const bf16x8*)&ldsA[rt * 16 + s][c * 32 + q * 8];

    f32x4 acc[16];
    f32x4 zero = {0.f, 0.f, 0.f, 0.f};
#pragma unroll
    for (int i = 0; i < 16; ++i) acc[i] = zero;

#pragma unroll
    for (int c = 0; c < 4; ++c)
#pragma unroll
      for (int rt = 0; rt < 4; ++rt)
#pragma unroll
        for (int ct = 0; ct < 4; ++ct)
          acc[rt * 4 + ct] = __builtin_amdgcn_mfma_f32_16x16x32_bf16(
              afrag[rt * 4 + c], bfrag[ct * 4 + c], acc[rt * 4 + ct], 0, 0, 0);

    // row = m0 + rt*16 + q*4 + r, col = (4w+ct)*16 + s -> pos s*8 + 4w+ct
#pragma unroll
    for (int rt = 0; rt < 4; ++rt) {
#pragma unroll
      for (int r = 0; r < 4; ++r) {
        int row = m0 + rt * 16 + q * 4 + r;
        if (row < M) {
          if (w < 2) {
            unsigned v = 0;
            v = __builtin_amdgcn_cvt_pk_fp8_f32(acc[rt * 4 + 0][r], acc[rt * 4 + 1][r], v, false);
            v = __builtin_amdgcn_cvt_pk_fp8_f32(acc[rt * 4 + 2][r], acc[rt * 4 + 3][r], v, true);
            *(unsigned*)&P[(size_t)row * 128 + s * 8 + w * 4] = v;
          } else {
            bf16x4 o;
#pragma unroll
            for (int ct = 0; ct < 4; ++ct) o[ct] = (__bf16)(acc[rt * 4 + ct][r] + breg[ct]);
            *(bf16x4*)&R[(size_t)row * 128 + s * 8 + (w - 2) * 4] = o;
          }
        }
      }
    }
    __syncthreads();
  }
}

// ------- fused layer: H1 = relu(mean_agg(P1)+R1); [P2|R2] = H1@[Wl2|Wr2]+b2 -------
// Persistent 512 blocks, 16-node tiles. Gather phase: 4 nodes/wave (one per 16-lane
// group), 8 edges in flight per group. H-tile staged in LDS (4 KB), then 16 MFMA/wave
// with register-resident Ws2 fragments. R2 written in place over R1 (block-private rows).

__global__ __launch_bounds__(256, 2) void fused_kernel(
    const unsigned char* __restrict__ P1, __bf16* R,            // R1 in, R2 out (in place)
    const int* __restrict__ offs, const int* __restrict__ deg,
    const int* __restrict__ ssrc,
    const __bf16* __restrict__ Wswz, const float* __restrict__ bias,
    unsigned char* __restrict__ P2, int n, int ntiles, int stride) {
  __shared__ __bf16 ldsH[16][136];
  const int t = threadIdx.x;
  const int lane = t & 63;
  const int w = t >> 6;
  const int q = lane >> 4;   // group index == MFMA quad
  const int s = lane & 15;

  bf16x8 bfrag[16];
#pragma unroll
  for (int ct = 0; ct < 4; ++ct)
#pragma unroll
    for (int c = 0; c < 4; ++c)
      bfrag[ct * 4 + c] =
          *(const bf16x8*)&Wswz[(size_t)((((w * 4 + ct) * 4 + c) * 64) + lane) * 8];

  float breg[4];
#pragma unroll
  for (int j = 0; j < 4; ++j)
    breg[j] = (w >= 2) ? bias[((w - 2) * 4 + j) * 16 + s] : 0.f;

  const unsigned char* Pb = P1 + (size_t)s * 8;

  for (int tile = blockIdx.x; tile < ntiles; tile += stride) {
    // ---- gather phase: this group's node ----
    int node = tile * 16 + w * 4 + q;
    int nc = min(node, n - 1);
    int start = offs[nc];
    int pend = offs[nc + 1];

    f32x2 a01 = {0.f, 0.f}, a23 = {0.f, 0.f}, a45 = {0.f, 0.f}, a67 = {0.f, 0.f};
    for (int cur = start; cur < pend; cur += 8) {
      uint4 sv = *(const uint4*)&ssrc[cur];
      uint2 v0 = *(const uint2*)(Pb + (size_t)sv.x * 128);
      uint2 v1 = *(const uint2*)(Pb + (size_t)sv.y * 128);
      uint2 v2 = *(const uint2*)(Pb + (size_t)sv.z * 128);
      uint2 v3 = *(const uint2*)(Pb + (size_t)sv.w * 128);
      if (cur + 4 < pend) {
        uint4 sw = *(const uint4*)&ssrc[cur + 4];
        uint2 u0 = *(const uint2*)(Pb + (size_t)sw.x * 128);
        uint2 u1 = *(const uint2*)(Pb + (size_t)sw.y * 128);
        uint2 u2 = *(const uint2*)(Pb + (size_t)sw.z * 128);
        uint2 u3 = *(const uint2*)(Pb + (size_t)sw.w * 128);
        a01 += __builtin_amdgcn_cvt_pk_f32_fp8(u0.x, false);
        a23 += __builtin_amdgcn_cvt_pk_f32_fp8(u0.x, true);
        a45 += __builtin_amdgcn_cvt_pk_f32_fp8(u0.y, false);
        a67 += __builtin_amdgcn_cvt_pk_f32_fp8(u0.y, true);
        a01 += __builtin_amdgcn_cvt_pk_f32_fp8(u1.x, false);
        a23 += __builtin_amdgcn_cvt_pk_f32_fp8(u1.x, true);
        a45 += __builtin_amdgcn_cvt_pk_f32_fp8(u1.y, false);
        a67 += __builtin_amdgcn_cvt_pk_f32_fp8(u1.y, true);
        a01 += __builtin_amdgcn_cvt_pk_f32_fp8(u2.x, false);
        a23 += __builtin_amdgcn_cvt_pk_f32_fp8(u2.x, true);
        a45 += __builtin_amdgcn_cvt_pk_f32_fp8(u2.y, false);
        a67 += __builtin_amdgcn_cvt_pk_f32_fp8(u2.y, true);
        a01 += __builtin_amdgcn_cvt_pk_f32_fp8(u3.x, false);
        a23 += __builtin_amdgcn_cvt_pk_f32_fp8(u3.x, true);
        a45 += __builtin_amdgcn_cvt_pk_f32_fp8(u3.y, false);
        a67 += __builtin_amdgcn_cvt_pk_f32_fp8(u3.y, true);
      }
      a01 += __builtin_amdgcn_cvt_pk_f32_fp8(v0.x, false);
      a23 += __builtin_amdgcn_cvt_pk_f32_fp8(v0.x, true);
      a45 += __builtin_amdgcn_cvt_pk_f32_fp8(v0.y, false);
      a67 += __builtin_amdgcn_cvt_pk_f32_fp8(v0.y, true);
      a01 += __builtin_amdgcn_cvt_pk_f32_fp8(v1.x, false);
      a23 += __builtin_amdgcn_cvt_pk_f32_fp8(v1.x, true);
      a45 += __builtin_amdgcn_cvt_pk_f32_fp8(v1.y, false);
      a67 += __builtin_amdgcn_cvt_pk_f32_fp8(v1.y, true);
      a01 += __builtin_amdgcn_cvt_pk_f32_fp8(v2.x, false);
      a23 += __builtin_amdgcn_cvt_pk_f32_fp8(v2.x, true);
      a45 += __builtin_amdgcn_cvt_pk_f32_fp8(v2.y, false);
      a67 += __builtin_amdgcn_cvt_pk_f32_fp8(v2.y, true);
      a01 += __builtin_amdgcn_cvt_pk_f32_fp8(v3.x, false);
      a23 += __builtin_amdgcn_cvt_pk_f32_fp8(v3.x, true);
      a45 += __builtin_amdgcn_cvt_pk_f32_fp8(v3.y, false);
      a67 += __builtin_amdgcn_cvt_pk_f32_fp8(v3.y, true);
    }

    int dg = deg[nc];
    float inv = 1.0f / (float)(dg > 0 ? dg : 1);
    bf16x8 rv = *(const bf16x8*)&R[(size_t)nc * 128 + s * 8];
    float acc1[8] = {a01[0], a01[1], a23[0], a23[1], a45[0], a45[1], a67[0], a67[1]};
    bf16x8 hh;
#pragma unroll
    for (int j = 0; j < 8; ++j)
      hh[j] = (__bf16)fmaxf(acc1[j] * inv + (float)rv[j], 0.f);

    *(bf16x8*)&ldsH[w * 4 + q][s * 8] = hh;
    __syncthreads();

    // ---- GEMM phase: 16 rows x 256 cols ----
    bf16x8 afrag[4];
#pragma unroll
    for (int c = 0; c < 4; ++c)
      afrag[c] = *(const bf16x8*)&ldsH[s][c * 32 + q * 8];

    f32x4 acc2[4];
    f32x4 zero = {0.f, 0.f, 0.f, 0.f};
#pragma unroll
    for (int i = 0; i < 4; ++i) acc2[i] = zero;

#pragma unroll
    for (int c = 0; c < 4; ++c)
#pragma unroll
      for (int ct = 0; ct < 4; ++ct)
        acc2[ct] = __builtin_amdgcn_mfma_f32_16x16x32_bf16(afrag[c], bfrag[ct * 4 + c],
                                                           acc2[ct], 0, 0, 0);

    // row = tile*16 + q*4 + r, col = (4w+ct)*16 + s -> pos s*8 + 4w+ct
#pragma unroll
    for (int r = 0; r < 4; ++r) {
      int row = tile * 16 + q * 4 + r;
      if (row < n) {
        if (w < 2) {
          unsigned v = 0;
          v = __builtin_amdgcn_cvt_pk_fp8_f32(acc2[0][r], acc2[1][r], v, false);
          v = __builtin_amdgcn_cvt_pk_fp8_f32(acc2[2][r], acc2[3][r], v, true);
          *(unsigned*)&P2[(size_t)row * 128 + s * 8 + w * 4] = v;
        } else {
          bf16x4 o;
#pragma unroll
          for (int ct = 0; ct < 4; ++ct) o[ct] = (__bf16)(acc2[ct][r] + breg[ct]);
          *(bf16x4*)&R[(size_t)row * 128 + s * 8 + (w - 2) * 4] = o;
        }
      }
    }
    __syncthreads();
  }
}

// ------------- final aggregation + heads: out from relu(mean_agg(P2)+R2) -------------
// 4 nodes per wave (one per 16-lane group), branch-free padded gather.

__global__ __launch_bounds__(256) void agg2_kernel(
    const unsigned char* __restrict__ P, const __bf16* __restrict__ R,
    const int* __restrict__ offs, const int* __restrict__ deg,
    const int* __restrict__ ssrc, float* __restrict__ out,
    const float* __restrict__ Wp, const float* __restrict__ Wd,
    const float* __restrict__ bp, const float* __restrict__ bd, int n) {
  int w4 = (int)((blockIdx.x * blockDim.x + threadIdx.x) >> 6);
  int lane = threadIdx.x & 63;
  int g = lane >> 4;
  int s = lane & 15;
  int node = w4 * 4 + g;
  int nc = min(node, n - 1);
  int start = offs[nc];
  int pend = offs[nc + 1];

  f32x2 a01 = {0.f, 0.f}, a23 = {0.f, 0.f}, a45 = {0.f, 0.f}, a67 = {0.f, 0.f};

  const unsigned char* Pb = P + (size_t)s * 8;
  for (int cur = start; cur < pend; cur += 4) {
    uint4 sv = *(const uint4*)&ssrc[cur];
    uint2 v0 = *(const uint2*)(Pb + (size_t)sv.x * 128);
    uint2 v1 = *(const uint2*)(Pb + (size_t)sv.y * 128);
    uint2 v2 = *(const uint2*)(Pb + (size_t)sv.z * 128);
    uint2 v3 = *(const uint2*)(Pb + (size_t)sv.w * 128);
    a01 += __builtin_amdgcn_cvt_pk_f32_fp8(v0.x, false);
    a23 += __builtin_amdgcn_cvt_pk_f32_fp8(v0.x, true);
    a45 += __builtin_amdgcn_cvt_pk_f32_fp8(v0.y, false);
    a67 += __builtin_amdgcn_cvt_pk_f32_fp8(v0.y, true);
    a01 += __builtin_amdgcn_cvt_pk_f32_fp8(v1.x, false);
    a23 += __builtin_amdgcn_cvt_pk_f32_fp8(v1.x, true);
    a45 += __builtin_amdgcn_cvt_pk_f32_fp8(v1.y, false);
    a67 += __builtin_amdgcn_cvt_pk_f32_fp8(v1.y, true);
    a01 += __builtin_amdgcn_cvt_pk_f32_fp8(v2.x, false);
    a23 += __builtin_amdgcn_cvt_pk_f32_fp8(v2.x, true);
    a45 += __builtin_amdgcn_cvt_pk_f32_fp8(v2.y, false);
    a67 += __builtin_amdgcn_cvt_pk_f32_fp8(v2.y, true);
    a01 += __builtin_amdgcn_cvt_pk_f32_fp8(v3.x, false);
    a23 += __builtin_amdgcn_cvt_pk_f32_fp8(v3.x, true);
    a45 += __builtin_amdgcn_cvt_pk_f32_fp8(v3.y, false);
    a67 += __builtin_amdgcn_cvt_pk_f32_fp8(v3.y, true);
  }

  int dg = deg[nc];
  float inv = 1.0f / (float)(dg > 0 ? dg : 1);

  bf16x8 rv = *(const bf16x8*)&R[(size_t)nc * 128 + s * 8];
  float acc[8] = {a01[0], a01[1], a23[0], a23[1], a45[0], a45[1], a67[0], a67[1]};
  float p = 0.f, dd = 0.f;
#pragma unroll
  for (int j = 0; j < 8; ++j) {
    float h = fmaxf(acc[j] * inv + (float)rv[j], 0.f);
    p += h * Wp[j * 16 + s];
    dd += h * Wd[j * 16 + s];
  }
  p += __shfl_xor(p, 1, 64);  p += __shfl_xor(p, 2, 64);
  p += __shfl_xor(p, 4, 64);  p += __shfl_xor(p, 8, 64);
  dd += __shfl_xor(dd, 1, 64); dd += __shfl_xor(dd, 2, 64);
  dd += __shfl_xor(dd, 4, 64); dd += __shfl_xor(dd, 8, 64);
  if (node < n && s == 0) {
    float preds = p + bp[0];
    float sg = 1.0f / (1.0f + __expf(-(dd + bd[0])));
    out[node] = preds - sg;
    out[n + node] = preds + sg;
  }
}

// ----------------------------------- launch -----------------------------------

extern "C" void kernel_launch(void* const* d_in, const int* in_sizes, int n_in,
                              void* d_out, int out_size, void* d_ws, size_t ws_size,
                              hipStream_t stream) {
  const float* x    = (const float*)d_in[0];
  const int*   ei   = (const int*)d_in[1];
  const float* Wl1 = (const float*)d_in[2];
  const float* Wr1 = (const float*)d_in[3];
  const float* b1  = (const float*)d_in[4];
  const float* Wl2 = (const float*)d_in[5];
  const float* Wr2 = (const float*)d_in[6];
  const float* b2  = (const float*)d_in[7];
  const float* Wp  = (const float*)d_in[8];
  const float* bp  = (const float*)d_in[9];
  const float* Wd  = (const float*)d_in[10];
  const float* bd  = (const float*)d_in[11];
  float* out = (float*)d_out;

  const int N = N_NODES, E = N_EDGES;
  const int* src = ei;
  const int* dst = ei + E;
  const size_t PADE = (size_t)E + 3 * (size_t)N + 64;

  char* w = (char*)d_ws;
  unsigned char* P1 = (unsigned char*)w; w += (size_t)(N + 1) * 128;  // fp8 + sentinel
  unsigned char* P2 = (unsigned char*)w; w += (size_t)(N + 1) * 128;  // fp8 + sentinel
  __bf16* Rbuf   = (__bf16*)w;   w += (size_t)N * 128 * 2;            // R1 -> R2 in place
  int* ssrc      = (int*)w;      w += PADE * 4;
  unsigned* pck  = (unsigned*)w; w += (size_t)NBUCK * BCAP * 4;       // 8.0 MB
  int* bcnt      = (int*)w;      w += 512 * 4;
  int* bbase     = (int*)w;      w += 512 * 4;
  int* pbt       = (int*)w;      w += 512 * 4;
  int* pcnt      = (int*)w;      w += (size_t)(N + 32) * 4;
  int* deg       = (int*)w;      w += (size_t)(N + 32) * 4;
  int* offs      = (int*)w;      w += (size_t)(N + 32) * 4;
  __bf16* Ws1    = (__bf16*)w;   w += 65536;
  __bf16* Ws2    = (__bf16*)w;   w += 65536;

  // graph preprocessing (shared by both layers)
  zerob_kernel<<<1, 512, 0, stream>>>(bcnt, (int*)(P1 + (size_t)N * 128),
                                      (int*)(P2 + (size_t)N * 128));
  wswz_kernel<<<256, 256, 0, stream>>>(Wl1, Wr1, Wl2, Wr2, Ws1, Ws2);
  partA_kernel<<<(E + ACHUNK - 1) / ACHUNK, 256, 0, stream>>>(src, dst, bcnt, pck, E);
  partBh_kernel<<<NBUCK, 256, 0, stream>>>(pck, bcnt, pcnt, deg, pbt, N);
  bscan_kernel<<<1, 512, 0, stream>>>(pbt, bbase, offs, N);
  partBs_kernel<<<NBUCK, 256, 0, stream>>>(pck, bcnt, bbase, pcnt, deg, offs, ssrc, N);

  const int TILES = (N + 63) / 64;   // 1563
  const int NT16  = (N + 15) / 16;   // 6250 (exact: N divisible by 16)
  const int GG = 512;
  // layer 1: P1 = x@Wl1 (fp8), R1 = x@Wr1 + b1
  gemm1_kernel<<<GG, 256, 0, stream>>>(x, Ws1, b1, P1, Rbuf, N, TILES, GG);
  // fused: H1 = relu(mean_agg(P1)+R1); P2 = H1@Wl2 (fp8), R2 = H1@Wr2 + b2 (in place)
  fused_kernel<<<GG, 256, 0, stream>>>(P1, Rbuf, offs, deg, ssrc, Ws2, b2, P2, N, NT16, GG);
  // final aggregation + heads
  agg2_kernel<<<NT16, 256, 0, stream>>>(P2, Rbuf, offs, deg, ssrc, out,
                                        Wp, Wd, bp, bd, N);
}